// Round 7
// baseline (128.461 us; speedup 1.0000x reference)
//
#include <hip/hip_runtime.h>

// GRU encoder, MI355X — R7.
// vs R5: ILP via two independent 16-row tiles per block (BB=32), interleaved in
// program order within each wave; weight frags shared. 256 blocks x 256 thr,
// 1 block/CU, 1 wave/SIMD (~240 VGPR). Trans floor ~770cy/SIMD/step; goal is to
// collapse the ~2000cy/step issue-idle by giving every stall an independent stream.

typedef __bf16 bf16x8 __attribute__((ext_vector_type(8)));
typedef float  f32x4  __attribute__((ext_vector_type(4)));
typedef int    int4v  __attribute__((ext_vector_type(4)));
typedef unsigned int uint4v __attribute__((ext_vector_type(4)));

#define NV   1000
#define EMB  64
#define HD   128
#define G3   384
#define SEQ  64
#define BB   32   // batch rows per block = 2 tiles x 16

#define SC_RZ (-1.4426950408889634f)   // -log2(e): sigmoid(s)=rcp(1+exp2(-log2e*s))
#define SC_N  ( 2.8853900817779268f)   // +2log2(e): tanh(v)=1-2*rcp(1+exp2(2log2e*v))

__device__ __forceinline__ float bfslot(uint4v w, int s) {   // s is unroll-constant
    const unsigned int word = w[s >> 1];
    const unsigned int bits = (s & 1) ? (word & 0xffff0000u) : (word << 16);
    return __builtin_bit_cast(float, bits);
}

__global__ void g_table_kernel(const float* __restrict__ embed,
                               const float* __restrict__ W_ih,
                               const float* __restrict__ b_ih,
                               const float* __restrict__ b_hh,
                               unsigned short* __restrict__ Gpk)
{
    __shared__ float emb[EMB];
    const int v = blockIdx.x;
    const int g = threadIdx.x;              // 0..383 = gate*128 + hid
    if (g < EMB) emb[g] = embed[v * EMB + g];
    __syncthreads();
    const float* wr = W_ih + g * EMB;
    float s = b_ih[g] + (g < 2 * HD ? b_hh[g] : 0.f);   // fold b_hh for r,z only
    #pragma unroll
    for (int e = 0; e < EMB; e += 4) {
        const float4 w4 = *(const float4*)(wr + e);
        s += w4.x * emb[e] + w4.y * emb[e + 1] + w4.z * emb[e + 2] + w4.w * emb[e + 3];
    }
    const int hid = g & 127, gate = g >> 7;
    s *= (gate < 2) ? SC_RZ : SC_N;                      // pre-scale for exp2-form gates
    const int cwi = hid >> 5, hti = (hid >> 4) & 1, c16i = hid & 15;
    Gpk[((v * 4 + cwi) * 16 + c16i) * 8 + (gate + 3 * hti)] =
        __builtin_bit_cast(unsigned short, (__bf16)s);
}

// pointwise GRU cell for one tile; writes h_t into the tile's other parity buffer
#define GRU_PW(A, XN, HR, TOFF, P)                                                 \
    _Pragma("unroll") for (int ht = 0; ht < 2; ++ht)                               \
      _Pragma("unroll") for (int j = 0; j < 4; ++j) {                              \
        const float r  = __builtin_amdgcn_rcpf(                                    \
            1.f + __builtin_amdgcn_exp2f(A[0][ht][j]));                            \
        const float zg = __builtin_amdgcn_rcpf(                                    \
            1.f + __builtin_amdgcn_exp2f(A[1][ht][j]));                            \
        const float v  = __builtin_fmaf(r, A[2][ht][j], XN[ht][j]);                \
        const float n  = __builtin_fmaf(-2.f,                                      \
            __builtin_amdgcn_rcpf(1.f + __builtin_amdgcn_exp2f(v)), 1.f);          \
        const float hn = __builtin_fmaf(zg, HR[ht][j] - n, n);                     \
        HR[ht][j] = hn;                                                            \
        *(unsigned short*)(hbase + (TOFF) + (1 - (P)) * 4096 + woff[ht][j]) =      \
            __builtin_bit_cast(unsigned short, (__bf16)hn);                        \
      }

// one GRU timestep for BOTH tiles. P = read-parity (compile-time), T = timestep.
#define GRU_STEP(P, T)                                                             \
  {                                                                                \
    int4v tk0 = {0, 0, 0, 0}, tk1 = {0, 0, 0, 0};                                  \
    if ((T) < SEQ - 1) {                                                           \
      tk0 = *(const int4v*)&xl[((T) + 1) * BB + quad * 4];                         \
      tk1 = *(const int4v*)&xl[((T) + 1) * BB + 16 + quad * 4];                    \
    }                                                                              \
    f32x4 a0[3][2], a1[3][2];                                                      \
    float xn0[2][4], xn1[2][4];                                                    \
    _Pragma("unroll") for (int ht = 0; ht < 2; ++ht)                               \
      _Pragma("unroll") for (int j = 0; j < 4; ++j) {                              \
        a0[0][ht][j] = bfslot(pf0[j], 3 * ht + 0);                                 \
        a0[1][ht][j] = bfslot(pf0[j], 3 * ht + 1);                                 \
        a0[2][ht][j] = ht ? bn1 : bn0;                                             \
        xn0[ht][j]   = bfslot(pf0[j], 3 * ht + 2);                                 \
        a1[0][ht][j] = bfslot(pf1[j], 3 * ht + 0);                                 \
        a1[1][ht][j] = bfslot(pf1[j], 3 * ht + 1);                                 \
        a1[2][ht][j] = ht ? bn1 : bn0;                                             \
        xn1[ht][j]   = bfslot(pf1[j], 3 * ht + 2);                                 \
      }                                                                            \
    _Pragma("unroll") for (int ks = 0; ks < 4; ++ks) {                             \
      const bf16x8 af = *(const bf16x8*)(hbase + (P) * 4096 + aoff[ks]);           \
      _Pragma("unroll") for (int gate = 0; gate < 3; ++gate)                       \
        _Pragma("unroll") for (int ht = 0; ht < 2; ++ht)                           \
          a0[gate][ht] = __builtin_amdgcn_mfma_f32_16x16x32_bf16(                  \
              af, wf[gate][ht][ks], a0[gate][ht], 0, 0, 0);                        \
    }                                                                              \
    _Pragma("unroll") for (int ks = 0; ks < 4; ++ks) {                             \
      const bf16x8 af = *(const bf16x8*)(hbase + 8192 + (P) * 4096 + aoff[ks]);    \
      _Pragma("unroll") for (int gate = 0; gate < 3; ++gate)                       \
        _Pragma("unroll") for (int ht = 0; ht < 2; ++ht)                           \
          a1[gate][ht] = __builtin_amdgcn_mfma_f32_16x16x32_bf16(                  \
              af, wf[gate][ht][ks], a1[gate][ht], 0, 0, 0);                        \
    }                                                                              \
    if ((T) < SEQ - 1) {                                                           \
      _Pragma("unroll") for (int j = 0; j < 4; ++j)                                \
        pf0[j] = *(const uint4v*)(gbase + (unsigned)(tk0[j] * 1024 + goff));       \
      _Pragma("unroll") for (int j = 0; j < 4; ++j)                                \
        pf1[j] = *(const uint4v*)(gbase + (unsigned)(tk1[j] * 1024 + goff));       \
    }                                                                              \
    GRU_PW(a0, xn0, hreg0, 0, P)                                                   \
    GRU_PW(a1, xn1, hreg1, 8192, P)                                                \
    asm volatile("s_waitcnt lgkmcnt(0)" ::: "memory");                             \
    __builtin_amdgcn_s_barrier();                                                  \
    __builtin_amdgcn_sched_barrier(0);                                             \
  }

__global__ __launch_bounds__(256, 1) void gru_kernel(
    const int*   __restrict__ x,    const unsigned short* __restrict__ Gpk,
    const float* __restrict__ Whh,  const float* __restrict__ bhh,
    const float* __restrict__ Wout, const float* __restrict__ bout,
    float* __restrict__ out)
{
    // layout: [tile][parity][4KB] (frag-permuted + XOR swizzle inside each 4KB)
    __shared__ unsigned short hA[2 * 2 * 16 * HD];   // 16 KB
    __shared__ int xl[SEQ * BB];                     // 8 KB, [t][row]

    const int tid  = threadIdx.x;
    const int lane = tid & 63;
    const int cw   = tid >> 6;      // wave id 0..3 = column team
    const int c16  = lane & 15;
    const int quad = lane >> 4;
    const int br0  = blockIdx.x * BB;

    // ---- stage tokens transposed: xl[t*BB + r] = x[(br0+r)*SEQ + t]
    #pragma unroll
    for (int i = 0; i < 8; ++i) {
        const int idx = i * 256 + tid;     // 0..2047
        const int r = idx >> 6;            // 0..31
        const int t = idx & 63;
        xl[t * BB + r] = x[(br0 + r) * SEQ + t];
    }
    // ---- zero both tiles' parity-0 h buffers (h0 = 0)
    {
        unsigned int* hA32 = (unsigned int*)hA;
        #pragma unroll
        for (int i = 0; i < 4; ++i) {
            hA32[tid + i * 256] = 0u;          // tile0 buf0: dwords 0..1023
            hA32[2048 + tid + i * 256] = 0u;   // tile1 buf0: dwords 2048..3071
        }
    }

    // ---- W_hh B-fragments (weight-stationary, gate-scaled; SHARED by both tiles)
    bf16x8 wf[3][2][4];
    #pragma unroll
    for (int gate = 0; gate < 3; ++gate)
    #pragma unroll
    for (int ht = 0; ht < 2; ++ht)
    #pragma unroll
    for (int ks = 0; ks < 4; ++ks) {
        const float sc = (gate < 2) ? SC_RZ : SC_N;
        const int col = gate * HD + cw * 32 + ht * 16 + c16;
        const float* p = Whh + col * HD + ks * 32 + quad * 4;
        const float4 a = *(const float4*)p;
        const float4 b = *(const float4*)(p + 16);
        bf16x8 f;
        f[0] = (__bf16)(sc * a.x); f[1] = (__bf16)(sc * a.y);
        f[2] = (__bf16)(sc * a.z); f[3] = (__bf16)(sc * a.w);
        f[4] = (__bf16)(sc * b.x); f[5] = (__bf16)(sc * b.y);
        f[6] = (__bf16)(sc * b.z); f[7] = (__bf16)(sc * b.w);
        wf[gate][ht][ks] = f;
    }

    const float bn0 = SC_N * bhh[2 * HD + cw * 32 + c16];        // scaled n-bias
    const float bn1 = SC_N * bhh[2 * HD + cw * 32 + 16 + c16];

    // ---- hoisted per-lane-constant LDS offsets (within a 4KB tile-parity buffer)
    int aoff[4];
    #pragma unroll
    for (int ks = 0; ks < 4; ++ks)
        aoff[ks] = c16 * 256 + ((ks * 64 + quad * 16) ^ ((c16 & 7) << 4));
    int woff[2][4];
    #pragma unroll
    for (int ht = 0; ht < 2; ++ht)
    #pragma unroll
    for (int j = 0; j < 4; ++j) {
        const int hid  = cw * 32 + ht * 16 + c16;
        const int sidx = ((hid >> 5) << 5) | (((hid & 15) >> 2) << 3)
                       | (((hid >> 4) & 1) << 2) | (hid & 3);
        const int row  = quad * 4 + j;
        woff[ht][j] = row * 256 + ((sidx * 2) ^ ((row & 7) << 4));
    }

    char* hbase = (char*)hA;
    const char* gbase = (const char*)Gpk;
    const int goff = cw * 256 + c16 * 16;

    float hreg0[2][4] = {{0.f, 0.f, 0.f, 0.f}, {0.f, 0.f, 0.f, 0.f}};
    float hreg1[2][4] = {{0.f, 0.f, 0.f, 0.f}, {0.f, 0.f, 0.f, 0.f}};
    const f32x4 z4 = {0.f, 0.f, 0.f, 0.f};

    __syncthreads();   // xl + hA zeros visible (one-time full drain is fine)

    // ---- preload xg for t=0, both tiles (single pf buffer each: consume-then-reload)
    uint4v pf0[4], pf1[4];
    {
        const int4v t0 = *(const int4v*)&xl[0 * BB + quad * 4];
        const int4v t1 = *(const int4v*)&xl[0 * BB + 16 + quad * 4];
        #pragma unroll
        for (int j = 0; j < 4; ++j)
            pf0[j] = *(const uint4v*)(gbase + (unsigned)(t0[j] * 1024 + goff));
        #pragma unroll
        for (int j = 0; j < 4; ++j)
            pf1[j] = *(const uint4v*)(gbase + (unsigned)(t1[j] * 1024 + goff));
    }

    for (int tt = 0; tt < SEQ; tt += 2) {
        GRU_STEP(0, tt);       // reads parity 0, writes parity 1 (both tiles)
        GRU_STEP(1, tt + 1);   // reads parity 1, writes parity 0
    }
    // after t=63 (odd): h_final in parity-0 buffers of both tiles.

    // ---- epilogue: out = h_final @ W_out^T + b_out (both tiles)
    bf16x8 wo[2][4];
    #pragma unroll
    for (int ht = 0; ht < 2; ++ht)
    #pragma unroll
    for (int ks = 0; ks < 4; ++ks) {
        const int col = cw * 32 + ht * 16 + c16;
        const float* p = Wout + col * HD + ks * 32 + quad * 4;
        const float4 a = *(const float4*)p;
        const float4 b = *(const float4*)(p + 16);
        bf16x8 f;
        f[0] = (__bf16)a.x; f[1] = (__bf16)a.y; f[2] = (__bf16)a.z; f[3] = (__bf16)a.w;
        f[4] = (__bf16)b.x; f[5] = (__bf16)b.y; f[6] = (__bf16)b.z; f[7] = (__bf16)b.w;
        wo[ht][ks] = f;
    }
    const float bo0 = bout[cw * 32 + c16];
    const float bo1 = bout[cw * 32 + 16 + c16];

    f32x4 oacc0[2] = {z4, z4}, oacc1[2] = {z4, z4};
    #pragma unroll
    for (int ks = 0; ks < 4; ++ks) {
        const bf16x8 af0 = *(const bf16x8*)(hbase + aoff[ks]);          // tile0 parity0
        const bf16x8 af1 = *(const bf16x8*)(hbase + 8192 + aoff[ks]);   // tile1 parity0
        #pragma unroll
        for (int ht = 0; ht < 2; ++ht) {
            oacc0[ht] = __builtin_amdgcn_mfma_f32_16x16x32_bf16(af0, wo[ht][ks], oacc0[ht], 0, 0, 0);
            oacc1[ht] = __builtin_amdgcn_mfma_f32_16x16x32_bf16(af1, wo[ht][ks], oacc1[ht], 0, 0, 0);
        }
    }
    #pragma unroll
    for (int ht = 0; ht < 2; ++ht) {
        const float bo_ = ht ? bo1 : bo0;
        const int col = cw * 32 + ht * 16 + c16;
        #pragma unroll
        for (int j = 0; j < 4; ++j) {
            const int row = br0 + quad * 4 + j;
            out[row * HD + col] = oacc0[ht][j] + bo_;
            out[(row + 16) * HD + col] = oacc1[ht][j] + bo_;
        }
    }
}

extern "C" void kernel_launch(void* const* d_in, const int* in_sizes, int n_in,
                              void* d_out, int out_size, void* d_ws, size_t ws_size,
                              hipStream_t stream) {
    const int*   x     = (const int*)  d_in[0];
    const float* embed = (const float*)d_in[1];
    const float* W_ih  = (const float*)d_in[2];
    const float* W_hh  = (const float*)d_in[3];
    const float* b_ih  = (const float*)d_in[4];
    const float* b_hh  = (const float*)d_in[5];
    const float* W_out = (const float*)d_in[6];
    const float* b_out = (const float*)d_in[7];
    float* outp = (float*)d_out;
    unsigned short* Gpk = (unsigned short*)d_ws;   // 1000*4*16*8*2B = 1.024 MB

    const int Bsz = in_sizes[0] / SEQ;             // 8192

    g_table_kernel<<<NV, G3, 0, stream>>>(embed, W_ih, b_ih, b_hh, Gpk);
    gru_kernel<<<Bsz / BB, 256, 0, stream>>>(x, Gpk, W_hh, b_hh, W_out, b_out, outp);
}

// Round 8
// 98.118 us; speedup vs baseline: 1.3092x; 1.3092x over previous
//
#include <hip/hip_runtime.h>

// GRU encoder, MI355X — R8.
// vs R5: 8-way gate-column split (16 cols/gate per wave), 512-thr blocks, BB=16,
// grid=512 -> 2 blocks/CU = 4 waves/SIMD (2x R5 TLP). Per-wave step: 12 MFMA,
// 4 PW elems, 4 ds_write_b16, 4 dwordx2 xg loads from repacked [v][w][c16][4] table.
// Carried: exp2-form gates (scales folded), xg/bn via MFMA C-init, swizzled dbuf
// LDS h, one raw s_barrier/step with lgkmcnt-only drain.

typedef __bf16 bf16x8 __attribute__((ext_vector_type(8)));
typedef float  f32x4  __attribute__((ext_vector_type(4)));
typedef int    int4v  __attribute__((ext_vector_type(4)));
typedef unsigned int uint2v __attribute__((ext_vector_type(2)));

#define NV   1000
#define EMB  64
#define HD   128
#define G3   384
#define SEQ  64
#define BB   16   // batch rows per block

#define SC_RZ (-1.4426950408889634f)   // -log2(e): sigmoid(s)=rcp(1+exp2(-log2e*s))
#define SC_N  ( 2.8853900817779268f)   // +2log2(e): tanh(v)=1-2*rcp(1+exp2(2log2e*v))

__device__ __forceinline__ float bflo(unsigned int word) {
    return __builtin_bit_cast(float, word << 16);
}
__device__ __forceinline__ float bfhi(unsigned int word) {
    return __builtin_bit_cast(float, word & 0xffff0000u);
}

// Gpk2[v][w][c16][slot]: slot 0..2 = scaled {xr',xz',xn'} for hid=w*16+c16, slot3 pad.
__global__ void g_table_kernel(const float* __restrict__ embed,
                               const float* __restrict__ W_ih,
                               const float* __restrict__ b_ih,
                               const float* __restrict__ b_hh,
                               unsigned short* __restrict__ Gpk)
{
    __shared__ float emb[EMB];
    const int v = blockIdx.x;
    const int g = threadIdx.x;              // 0..383 = gate*128 + hid
    if (g < EMB) emb[g] = embed[v * EMB + g];
    __syncthreads();
    const float* wr = W_ih + g * EMB;
    float s = b_ih[g] + (g < 2 * HD ? b_hh[g] : 0.f);   // fold b_hh for r,z only
    #pragma unroll
    for (int e = 0; e < EMB; e += 4) {
        const float4 w4 = *(const float4*)(wr + e);
        s += w4.x * emb[e] + w4.y * emb[e + 1] + w4.z * emb[e + 2] + w4.w * emb[e + 3];
    }
    const int hid = g & 127, gate = g >> 7;
    s *= (gate < 2) ? SC_RZ : SC_N;                      // pre-scale for exp2-form gates
    const int w8 = hid >> 4, c16i = hid & 15;
    Gpk[((v * 8 + w8) * 16 + c16i) * 4 + gate] =
        __builtin_bit_cast(unsigned short, (__bf16)s);
}

// one GRU timestep. P = read-parity (compile-time), T = timestep.
#define GRU_STEP(P, T)                                                             \
  {                                                                                \
    int4v tk = {0, 0, 0, 0};                                                       \
    if ((T) < SEQ - 1) tk = *(const int4v*)&xl[((T) + 1) * BB + quad * 4];         \
    f32x4 acc[3];                                                                  \
    float xn_[4];                                                                  \
    _Pragma("unroll") for (int j = 0; j < 4; ++j) {                                \
      acc[0][j] = bflo(pf[j][0]);    /* xr' */                                     \
      acc[1][j] = bfhi(pf[j][0]);    /* xz' */                                     \
      acc[2][j] = bnw;               /* bn' */                                     \
      xn_[j]    = bflo(pf[j][1]);    /* xn' */                                     \
    }                                                                              \
    _Pragma("unroll") for (int ks = 0; ks < 4; ++ks) {                             \
      const bf16x8 af = *(const bf16x8*)(hbase + (P) * 4096 + aoff[ks]);           \
      _Pragma("unroll") for (int gate = 0; gate < 3; ++gate)                       \
        acc[gate] = __builtin_amdgcn_mfma_f32_16x16x32_bf16(                       \
            af, wf[gate][ks], acc[gate], 0, 0, 0);                                 \
    }                                                                              \
    if ((T) < SEQ - 1) {                                                           \
      _Pragma("unroll") for (int j = 0; j < 4; ++j)                                \
        pf[j] = *(const uint2v*)(gbase + (unsigned)(tk[j] * 1024 + goff));         \
    }                                                                              \
    _Pragma("unroll") for (int j = 0; j < 4; ++j) {                                \
      const float r  = __builtin_amdgcn_rcpf(                                      \
          1.f + __builtin_amdgcn_exp2f(acc[0][j]));                                \
      const float zg = __builtin_amdgcn_rcpf(                                      \
          1.f + __builtin_amdgcn_exp2f(acc[1][j]));                                \
      const float v  = __builtin_fmaf(r, acc[2][j], xn_[j]);                       \
      const float n  = __builtin_fmaf(-2.f,                                        \
          __builtin_amdgcn_rcpf(1.f + __builtin_amdgcn_exp2f(v)), 1.f);            \
      const float hn = __builtin_fmaf(zg, hreg[j] - n, n);                         \
      hreg[j] = hn;                                                                \
      *(unsigned short*)(hbase + (1 - (P)) * 4096 + woff[j]) =                     \
          __builtin_bit_cast(unsigned short, (__bf16)hn);                          \
    }                                                                              \
    asm volatile("s_waitcnt lgkmcnt(0)" ::: "memory");                             \
    __builtin_amdgcn_s_barrier();                                                  \
    __builtin_amdgcn_sched_barrier(0);                                             \
  }

__global__ __launch_bounds__(512, 4) void gru_kernel(
    const int*   __restrict__ x,    const unsigned short* __restrict__ Gpk,
    const float* __restrict__ Whh,  const float* __restrict__ bhh,
    const float* __restrict__ Wout, const float* __restrict__ bout,
    float* __restrict__ out)
{
    __shared__ unsigned short hA[2 * BB * HD];   // 2 x 4KB, frag-permuted + XOR swizzle
    __shared__ int xl[SEQ * BB];                 // 4KB, [t][row]

    const int tid  = threadIdx.x;
    const int lane = tid & 63;
    const int w    = tid >> 6;      // wave id 0..7 = 16-col team (per gate)
    const int c16  = lane & 15;
    const int quad = lane >> 4;
    const int br0  = blockIdx.x * BB;

    // ---- stage tokens transposed: xl[t*BB + r] = x[(br0+r)*SEQ + t]
    #pragma unroll
    for (int i = 0; i < 2; ++i) {
        const int idx = i * 512 + tid;     // 0..1023
        const int r = idx >> 6;            // 0..15
        const int t = idx & 63;
        xl[t * BB + r] = x[(br0 + r) * SEQ + t];
    }
    // ---- zero parity-0 h buffer (h0 = 0): 1024 dwords
    {
        unsigned int* hA32 = (unsigned int*)hA;
        #pragma unroll
        for (int i = 0; i < 2; ++i)
            hA32[i * 512 + tid] = 0u;
    }

    // ---- W_hh B-fragments: cols gate*128 + w*16 + c16 (gate-scaled)
    bf16x8 wf[3][4];
    #pragma unroll
    for (int gate = 0; gate < 3; ++gate)
    #pragma unroll
    for (int ks = 0; ks < 4; ++ks) {
        const float sc = (gate < 2) ? SC_RZ : SC_N;
        const int col = gate * HD + w * 16 + c16;
        const float* p = Whh + col * HD + ks * 32 + quad * 4;
        const float4 a = *(const float4*)p;
        const float4 b = *(const float4*)(p + 16);
        bf16x8 f;
        f[0] = (__bf16)(sc * a.x); f[1] = (__bf16)(sc * a.y);
        f[2] = (__bf16)(sc * a.z); f[3] = (__bf16)(sc * a.w);
        f[4] = (__bf16)(sc * b.x); f[5] = (__bf16)(sc * b.y);
        f[6] = (__bf16)(sc * b.z); f[7] = (__bf16)(sc * b.w);
        wf[gate][ks] = f;
    }

    const float bnw = SC_N * bhh[2 * HD + w * 16 + c16];   // scaled n-bias, this col

    // ---- hoisted per-lane-constant LDS offsets
    int aoff[4];
    #pragma unroll
    for (int ks = 0; ks < 4; ++ks)
        aoff[ks] = c16 * 256 + ((ks * 64 + quad * 16) ^ ((c16 & 7) << 4));
    int woff[4];
    {
        const int hid  = w * 16 + c16;
        const int sidx = ((hid >> 5) << 5) | (((hid & 15) >> 2) << 3)
                       | (((hid >> 4) & 1) << 2) | (hid & 3);
        #pragma unroll
        for (int j = 0; j < 4; ++j) {
            const int row = quad * 4 + j;
            woff[j] = row * 256 + ((sidx * 2) ^ ((row & 7) << 4));
        }
    }

    char* hbase = (char*)hA;
    const char* gbase = (const char*)Gpk;
    const int goff = w * 128 + c16 * 8;    // byte offset within a 1024B table row

    float hreg[4] = {0.f, 0.f, 0.f, 0.f};
    const f32x4 z4 = {0.f, 0.f, 0.f, 0.f};

    __syncthreads();   // xl + hA zeros visible (one-time full drain is fine)

    // ---- preload xg for t=0
    uint2v pf[4];
    {
        const int4v tk0 = *(const int4v*)&xl[0 * BB + quad * 4];
        #pragma unroll
        for (int j = 0; j < 4; ++j)
            pf[j] = *(const uint2v*)(gbase + (unsigned)(tk0[j] * 1024 + goff));
    }

    for (int tt = 0; tt < SEQ; tt += 2) {
        GRU_STEP(0, tt);       // reads parity 0, writes parity 1
        GRU_STEP(1, tt + 1);   // reads parity 1, writes parity 0
    }
    // after t=63 (odd): h_final in parity-0 buffer.

    // ---- epilogue: out = h_final @ W_out^T + b_out (wave's 16 cols)
    bf16x8 wo[4];
    #pragma unroll
    for (int ks = 0; ks < 4; ++ks) {
        const int col = w * 16 + c16;
        const float* p = Wout + col * HD + ks * 32 + quad * 4;
        const float4 a = *(const float4*)p;
        const float4 b = *(const float4*)(p + 16);
        bf16x8 f;
        f[0] = (__bf16)a.x; f[1] = (__bf16)a.y; f[2] = (__bf16)a.z; f[3] = (__bf16)a.w;
        f[4] = (__bf16)b.x; f[5] = (__bf16)b.y; f[6] = (__bf16)b.z; f[7] = (__bf16)b.w;
        wo[ks] = f;
    }
    const float bow = bout[w * 16 + c16];

    f32x4 oacc = z4;
    #pragma unroll
    for (int ks = 0; ks < 4; ++ks) {
        const bf16x8 af = *(const bf16x8*)(hbase + aoff[ks]);   // parity 0
        oacc = __builtin_amdgcn_mfma_f32_16x16x32_bf16(af, wo[ks], oacc, 0, 0, 0);
    }
    #pragma unroll
    for (int j = 0; j < 4; ++j) {
        const int row = br0 + quad * 4 + j;
        out[row * HD + w * 16 + c16] = oacc[j] + bow;
    }
}

extern "C" void kernel_launch(void* const* d_in, const int* in_sizes, int n_in,
                              void* d_out, int out_size, void* d_ws, size_t ws_size,
                              hipStream_t stream) {
    const int*   x     = (const int*)  d_in[0];
    const float* embed = (const float*)d_in[1];
    const float* W_ih  = (const float*)d_in[2];
    const float* W_hh  = (const float*)d_in[3];
    const float* b_ih  = (const float*)d_in[4];
    const float* b_hh  = (const float*)d_in[5];
    const float* W_out = (const float*)d_in[6];
    const float* b_out = (const float*)d_in[7];
    float* outp = (float*)d_out;
    unsigned short* Gpk = (unsigned short*)d_ws;   // 1000*8*16*4*2B = 1.024 MB

    const int Bsz = in_sizes[0] / SEQ;             // 8192

    g_table_kernel<<<NV, G3, 0, stream>>>(embed, W_ih, b_ih, b_hh, Gpk);
    gru_kernel<<<Bsz / BB, 512, 0, stream>>>(x, Gpk, W_hh, b_hh, W_out, b_out, outp);
}